// Round 1
// baseline (296.470 us; speedup 1.0000x reference)
//
#include <hip/hip_runtime.h>

// QuantileLoss: mean over concat([ (preds[:,:3]-target[:,:3])^2 (3N), lower (N), lower (N) ])
// lower = p3>p2 ? 1000 : (p3 > 0.95*t2 ? 0 : (p3-0.95*t2)^2)
// => scalar = ( sum_rows[ mse3 + 2*lower ] ) / (5N)
//
// Memory-bound streaming reduction: 256 MiB read, ~42us floor @ 6.3 TB/s.
// lcm(5,4)=20: 1 thread handles 4 rows => 5x float4 (preds) + 3x float4 (target),
// all 16B-aligned, fully coalesced.

#define NROWS 8388608  // 2^23

__global__ void __launch_bounds__(256) qloss_partial(
    const float* __restrict__ preds,
    const float* __restrict__ target,
    double* __restrict__ ws)
{
    const int ngroups = NROWS / 4;  // 2,097,152 groups of 4 rows
    const int tid = blockIdx.x * blockDim.x + threadIdx.x;
    const int stride = gridDim.x * blockDim.x;

    double acc = 0.0;

    for (int g = tid; g < ngroups; g += stride) {
        const float4* p4 = (const float4*)(preds + (size_t)g * 20);
        const float4* t4 = (const float4*)(target + (size_t)g * 12);

        float p[20];
        float t[12];
        *(float4*)(p + 0)  = p4[0];
        *(float4*)(p + 4)  = p4[1];
        *(float4*)(p + 8)  = p4[2];
        *(float4*)(p + 12) = p4[3];
        *(float4*)(p + 16) = p4[4];
        *(float4*)(t + 0)  = t4[0];
        *(float4*)(t + 4)  = t4[1];
        *(float4*)(t + 8)  = t4[2];

        float sum = 0.0f;
        #pragma unroll
        for (int r = 0; r < 4; ++r) {
            const float a0 = p[5*r + 0] - t[3*r + 0];
            const float a1 = p[5*r + 1] - t[3*r + 1];
            const float a2 = p[5*r + 2] - t[3*r + 2];
            const float m  = a0*a0 + a1*a1 + a2*a2;

            const float pp2 = p[5*r + 2];
            const float pp3 = p[5*r + 3];
            const float q   = t[3*r + 2] * 0.95f;
            const float d   = pp3 - q;
            const float lower = (pp3 > pp2) ? 1000.0f
                              : ((pp3 > q) ? 0.0f : d * d);
            sum += m + 2.0f * lower;
        }
        acc += (double)sum;
    }

    // 64-lane wave reduce (wave = 64 on CDNA)
    #pragma unroll
    for (int off = 32; off > 0; off >>= 1)
        acc += __shfl_down(acc, off, 64);

    __shared__ double lds[4];  // 256 threads = 4 waves
    const int lane = threadIdx.x & 63;
    const int wave = threadIdx.x >> 6;
    if (lane == 0) lds[wave] = acc;
    __syncthreads();

    if (threadIdx.x == 0) {
        double s = lds[0] + lds[1] + lds[2] + lds[3];
        atomicAdd(ws, s);  // device-scope by default; one per block
    }
}

__global__ void qloss_final(const double* __restrict__ ws, float* __restrict__ out)
{
    *out = (float)(*ws / (5.0 * (double)NROWS));
}

extern "C" void kernel_launch(void* const* d_in, const int* in_sizes, int n_in,
                              void* d_out, int out_size, void* d_ws, size_t ws_size,
                              hipStream_t stream)
{
    const float* preds  = (const float*)d_in[0];
    const float* target = (const float*)d_in[1];
    float* out  = (float*)d_out;
    double* ws  = (double*)d_ws;

    // d_ws is re-poisoned to 0xAA before every timed launch — zero the accumulator.
    hipMemsetAsync(ws, 0, sizeof(double), stream);

    // 2048 blocks x 256 threads = 524288 threads; 4 groups (16 rows) per thread.
    // 8 blocks/CU on 256 CUs -> 32 waves/CU (full occupancy).
    qloss_partial<<<2048, 256, 0, stream>>>(preds, target, ws);
    qloss_final<<<1, 1, 0, stream>>>(ws, out);
}